// Round 8
// baseline (1527.880 us; speedup 1.0000x reference)
//
#include <hip/hip_runtime.h>
#include <hip/hip_bf16.h>

#define B_SZ 4096
#define FEAT 40960
#define HID  1024
#define L1N  64
#define L2N  32
#define IDX_CAP 128
#define W_SCALE 64.0f
#define W_INV   0.015625f

typedef float floatx2 __attribute__((ext_vector_type(2)));
typedef float floatx4 __attribute__((ext_vector_type(4)));

static __device__ __forceinline__ unsigned short f2bf(float x) {
    __hip_bfloat16 h = __float2bfloat16(x);
    return *reinterpret_cast<unsigned short*>(&h);
}
static __device__ __forceinline__ float bf2f_lo(unsigned int u) {
    return __uint_as_float(u << 16);
}
static __device__ __forceinline__ float bf2f_hi(unsigned int u) {
    return __uint_as_float(u & 0xffff0000u);
}
static __device__ __forceinline__ unsigned int packbf(float lo, float hi) {
    return (unsigned int)f2bf(lo) | ((unsigned int)f2bf(hi) << 16);
}
static __device__ __forceinline__ float clipf(float x) {
    return fminf(fmaxf(x, 0.0f), 1.0f);
}

// ---------------------------------------------------------------------------
// Kernel 1: transpose ft_w [HID,FEAT] fp32 -> ftwT8 [FEAT][HID] fp8 e4m3
// (x64 scale). Small (~35 us) and must complete before any gather.
// ---------------------------------------------------------------------------
__global__ __launch_bounds__(256) void transpose_fp8(
    const float* __restrict__ ftw, unsigned char* __restrict__ ftwT8) {
    __shared__ float tile[32][65];
    const int t  = threadIdx.x;
    const int tx = t & 31;           // 0..31
    const int ty = t >> 5;           // 0..7
    const int f0 = (blockIdx.x % (FEAT / 32)) * 32;
    const int h0 = (blockIdx.x / (FEAT / 32)) * 64;
#pragma unroll
    for (int i = 0; i < 8; ++i) {
        int h = ty + 8 * i;          // 0..63
        tile[tx][h] = ftw[(size_t)(h0 + h) * FEAT + f0 + tx] * W_SCALE;
    }
    __syncthreads();
    if (tx < 16) {
#pragma unroll
        for (int i = 0; i < 4; ++i) {
            int f = ty + 8 * i;      // 0..31
            unsigned int pk = 0;
            pk = __builtin_amdgcn_cvt_pk_fp8_f32(tile[f][4 * tx + 0], tile[f][4 * tx + 1], pk, false);
            pk = __builtin_amdgcn_cvt_pk_fp8_f32(tile[f][4 * tx + 2], tile[f][4 * tx + 3], pk, true);
            ((unsigned int*)(ftwT8 + (size_t)(f0 + f) * HID + h0))[tx] = pk;
        }
    }
}

// ---------------------------------------------------------------------------
// Kernel 2: fused scan + gather + MLP, one block per batch row.
// The scan's 320 KB/row HBM stream is the long pole; the gather's L3 reads
// (ftwT8, 40 MB resident) and the MLP's L2/VALU work hide under it across
// the ~4096 resident-and-queued blocks. LDS ~7 KB -> occupancy VGPR-bound.
// ---------------------------------------------------------------------------
__global__ __launch_bounds__(256) void nnue_row(
    const float* __restrict__ wf, const float* __restrict__ bfeat,
    const float* __restrict__ stm, const unsigned char* __restrict__ ftwT8,
    const float* __restrict__ ftb,
    const float* __restrict__ l1w, const float* __restrict__ l1b,
    const float* __restrict__ l2w, const float* __restrict__ l2b,
    const float* __restrict__ l3w, const float* __restrict__ l3b,
    float* __restrict__ out) {

    __shared__ int idxs[2][IDX_CAP];            // 1 KB
    __shared__ int cnts[2];
    __shared__ unsigned int h1p[HID];           // 4 KB packed bf16 (2048 vals)
    __shared__ float part[4 * L1N];             // 1 KB
    __shared__ float h2s[L1N];
    __shared__ float h3s[L2N];

    const int t = threadIdx.x;
    const int row = blockIdx.x;

    if (t < 2) cnts[t] = 0;
    __syncthreads();

    // --- scan both perspectives (one-pass stream; nontemporal to spare L2)
#pragma unroll
    for (int pp = 0; pp < 2; ++pp) {
        const floatx4* s4 = (const floatx4*)((pp ? bfeat : wf) + (size_t)row * FEAT);
#pragma unroll 4
        for (int it = 0; it < (FEAT / 4) / 256; ++it) {
            int i4 = it * 256 + t;
            floatx4 v = __builtin_nontemporal_load(&s4[i4]);
            int base = i4 * 4;
            if (v.x != 0.f) { int p = atomicAdd(&cnts[pp], 1); if (p < IDX_CAP) idxs[pp][p] = base + 0; }
            if (v.y != 0.f) { int p = atomicAdd(&cnts[pp], 1); if (p < IDX_CAP) idxs[pp][p] = base + 1; }
            if (v.z != 0.f) { int p = atomicAdd(&cnts[pp], 1); if (p < IDX_CAP) idxs[pp][p] = base + 2; }
            if (v.w != 0.f) { int p = atomicAdd(&cnts[pp], 1); if (p < IDX_CAP) idxs[pp][p] = base + 3; }
        }
    }
    __syncthreads();

    // --- gather: thread t owns h = 4t..4t+3 (one uint = 4 fp8 per feature)
    const int nw = min(cnts[0], IDX_CAP);
    const int nb = min(cnts[1], IDX_CAP);
    float4 bias = ((const float4*)ftb)[t];
    float aw0 = bias.x * W_SCALE, aw1 = bias.y * W_SCALE;
    float aw2 = bias.z * W_SCALE, aw3 = bias.w * W_SCALE;
    float ab0 = aw0, ab1 = aw1, ab2 = aw2, ab3 = aw3;

#pragma unroll 4
    for (int i = 0; i < nw; ++i) {
        unsigned int u = ((const unsigned int*)(ftwT8 + (size_t)idxs[0][i] * HID))[t];
        floatx2 lo = __builtin_amdgcn_cvt_pk_f32_fp8(u, false);
        floatx2 hi = __builtin_amdgcn_cvt_pk_f32_fp8(u, true);
        aw0 += lo.x; aw1 += lo.y; aw2 += hi.x; aw3 += hi.y;
    }
#pragma unroll 4
    for (int i = 0; i < nb; ++i) {
        unsigned int u = ((const unsigned int*)(ftwT8 + (size_t)idxs[1][i] * HID))[t];
        floatx2 lo = __builtin_amdgcn_cvt_pk_f32_fp8(u, false);
        floatx2 hi = __builtin_amdgcn_cvt_pk_f32_fp8(u, true);
        ab0 += lo.x; ab1 += lo.y; ab2 += hi.x; ab3 += hi.y;
    }

    // --- stm select + unscale + clip -> packed bf16 LDS
    {
        const bool wfirst = (stm[row] != 0.0f);
        float f0 = (wfirst ? aw0 : ab0) * W_INV, f1 = (wfirst ? aw1 : ab1) * W_INV;
        float f2 = (wfirst ? aw2 : ab2) * W_INV, f3 = (wfirst ? aw3 : ab3) * W_INV;
        float s0 = (wfirst ? ab0 : aw0) * W_INV, s1 = (wfirst ? ab1 : aw1) * W_INV;
        float s2 = (wfirst ? ab2 : aw2) * W_INV, s3 = (wfirst ? ab3 : aw3) * W_INV;
        h1p[2 * t]           = packbf(clipf(f0), clipf(f1));
        h1p[2 * t + 1]       = packbf(clipf(f2), clipf(f3));
        h1p[512 + 2 * t]     = packbf(clipf(s0), clipf(s1));
        h1p[512 + 2 * t + 1] = packbf(clipf(s2), clipf(s3));
    }
    __syncthreads();

    // --- l1: k = t&63 (neuron), p = t>>6 (wave-uniform 512-wide K-slice)
    {
        const int k = t & 63, p = t >> 6;
        float a = 0.f;
        const float4* w4 = (const float4*)(l1w + (size_t)k * 2 * HID + (size_t)p * 512);
        const int qbase = p * 256;
        for (int jj = 0; jj < 128; ++jj) {
            float4 w = w4[jj];
            int q = qbase + 2 * jj;
            unsigned int u0 = h1p[q], u1 = h1p[q + 1];
            a += w.x * bf2f_lo(u0) + w.y * bf2f_hi(u0) + w.z * bf2f_lo(u1) + w.w * bf2f_hi(u1);
        }
        part[p * L1N + k] = a;
    }
    __syncthreads();
    if (t < L1N) {
        h2s[t] = clipf(part[t] + part[L1N + t] + part[2 * L1N + t] + part[3 * L1N + t] + l1b[t]);
    }
    __syncthreads();

    // --- l2 (32 threads)
    if (t < L2N) {
        float a = l2b[t];
        const float4* w4 = (const float4*)(l2w + t * L1N);
        const float4* h4 = (const float4*)h2s;
#pragma unroll
        for (int j = 0; j < L1N / 4; ++j) {
            float4 w = w4[j]; float4 h = h4[j];
            a += w.x * h.x + w.y * h.y + w.z * h.z + w.w * h.w;
        }
        h3s[t] = clipf(a);
    }
    __syncthreads();

    // --- l3 + sigmoid (thread 0)
    if (t == 0) {
        float raw = l3b[0];
#pragma unroll
        for (int j = 0; j < L2N; ++j) raw += h3s[j] * l3w[j];
        out[row] = 1.0f / (1.0f + expf(-raw));
        out[B_SZ + row] = raw;
    }
}

// ---------------------------------------------------------------------------
extern "C" void kernel_launch(void* const* d_in, const int* in_sizes, int n_in,
                              void* d_out, int out_size, void* d_ws, size_t ws_size,
                              hipStream_t stream) {
    const float* wf    = (const float*)d_in[0];
    const float* bfeat = (const float*)d_in[1];
    const float* stm   = (const float*)d_in[2];
    const float* ftw   = (const float*)d_in[3];
    const float* ftb   = (const float*)d_in[4];
    const float* l1w   = (const float*)d_in[5];
    const float* l1b   = (const float*)d_in[6];
    const float* l2w   = (const float*)d_in[7];
    const float* l2b   = (const float*)d_in[8];
    const float* l3w   = (const float*)d_in[9];
    const float* l3b   = (const float*)d_in[10];
    float* out = (float*)d_out;

    // ws layout: ftwT8 fp8 [FEAT*HID] (40 MB)
    unsigned char* ftwT8 = (unsigned char*)d_ws;

    transpose_fp8<<<(FEAT / 32) * (HID / 64), 256, 0, stream>>>(ftw, ftwT8);
    nnue_row<<<B_SZ, 256, 0, stream>>>(wf, bfeat, stm, ftwT8, ftb,
                                       l1w, l1b, l2w, l2b, l3w, l3b, out);
}